// Round 1
// baseline (1797.235 us; speedup 1.0000x reference)
//
#include <hip/hip_runtime.h>
#include <math.h>

#define NTOK 4096
#define DIM  1024
#define HALF 512
#define NKEY 512
#define TOPK 32

// ---------- frontier candidate tables: (a+1)*(b+1) <= 32, 119 entries ----------
__device__ __constant__ signed char CAND_A[128] = {
  0,0,0,0,0,0,0,0,0,0,0,0,0,0,0,0,0,0,0,0,0,0,0,0,0,0,0,0,0,0,0,0,
  1,1,1,1,1,1,1,1,1,1,1,1,1,1,1,1,
  2,2,2,2,2,2,2,2,2,2,
  3,3,3,3,3,3,3,3,
  4,4,4,4,4,4,
  5,5,5,5,5,
  6,6,6,6,
  7,7,7,7,
  8,8,8,
  9,9,9,
  10,10, 11,11, 12,12, 13,13, 14,14, 15,15,
  16,17,18,19,20,21,22,23,24,25,26,27,28,29,30,31,
  0,0,0,0,0,0,0,0,0 };
__device__ __constant__ signed char CAND_B[128] = {
  0,1,2,3,4,5,6,7,8,9,10,11,12,13,14,15,16,17,18,19,20,21,22,23,24,25,26,27,28,29,30,31,
  0,1,2,3,4,5,6,7,8,9,10,11,12,13,14,15,
  0,1,2,3,4,5,6,7,8,9,
  0,1,2,3,4,5,6,7,
  0,1,2,3,4,5,
  0,1,2,3,4,
  0,1,2,3,
  0,1,2,3,
  0,1,2,
  0,1,2,
  0,1, 0,1, 0,1, 0,1, 0,1, 0,1,
  0,0,0,0,0,0,0,0,0,0,0,0,0,0,0,0,
  0,0,0,0,0,0,0,0,0 };

// ---------------- NT fp32 GEMM: out[m,n] = sum_k A[m,k]*B[n,k] + bias[n] ----------------
// BM=128, BN=64, BK=16, 256 threads, 8x4 per thread. mode: 0=none, 1=silu
__global__ __launch_bounds__(256) void gemm_nt(const float* __restrict__ A,
                                               const float* __restrict__ B,
                                               const float* __restrict__ bias,
                                               float* __restrict__ C,
                                               int M, int N, int K, int mode)
{
  constexpr int BM = 128, BN = 64, BK = 16;
  __shared__ float As[BK][BM];
  __shared__ float Bs[BK][BN];
  const int tid = threadIdx.x;
  const int bm = blockIdx.y * BM, bn = blockIdx.x * BN;
  const int tm = tid >> 4, tn = tid & 15;        // 16 x 16 thread grid
  const int lr = tid >> 2, lc = (tid & 3) * 4;   // loader: row 0..63, k-group
  float acc[8][4];
#pragma unroll
  for (int i = 0; i < 8; i++)
#pragma unroll
    for (int j = 0; j < 4; j++) acc[i][j] = 0.f;

  const float* Arow0 = A + (size_t)(bm + lr) * K + lc;
  const float* Arow1 = Arow0 + (size_t)64 * K;
  const float* Brow  = B + (size_t)(bn + lr) * K + lc;

  for (int k0 = 0; k0 < K; k0 += BK) {
    float4 a0 = *(const float4*)(Arow0 + k0);
    float4 a1 = *(const float4*)(Arow1 + k0);
    float4 b0 = *(const float4*)(Brow + k0);
    __syncthreads();
    As[lc + 0][lr] = a0.x; As[lc + 1][lr] = a0.y; As[lc + 2][lr] = a0.z; As[lc + 3][lr] = a0.w;
    As[lc + 0][lr + 64] = a1.x; As[lc + 1][lr + 64] = a1.y; As[lc + 2][lr + 64] = a1.z; As[lc + 3][lr + 64] = a1.w;
    Bs[lc + 0][lr] = b0.x; Bs[lc + 1][lr] = b0.y; Bs[lc + 2][lr] = b0.z; Bs[lc + 3][lr] = b0.w;
    __syncthreads();
#pragma unroll
    for (int kk = 0; kk < BK; kk++) {
      float4 av0 = *(const float4*)&As[kk][tm * 8];
      float4 av1 = *(const float4*)&As[kk][tm * 8 + 4];
      float4 bv  = *(const float4*)&Bs[kk][tn * 4];
      float a[8] = {av0.x, av0.y, av0.z, av0.w, av1.x, av1.y, av1.z, av1.w};
      float b[4] = {bv.x, bv.y, bv.z, bv.w};
#pragma unroll
      for (int i = 0; i < 8; i++)
#pragma unroll
        for (int j = 0; j < 4; j++) acc[i][j] += a[i] * b[j];
    }
  }
  float4 bb = *(const float4*)(bias + bn + tn * 4);
#pragma unroll
  for (int i = 0; i < 8; i++) {
    int row = bm + tm * 8 + i;
    float4 o;
    o.x = acc[i][0] + bb.x; o.y = acc[i][1] + bb.y;
    o.z = acc[i][2] + bb.z; o.w = acc[i][3] + bb.w;
    if (mode == 1) {
      o.x = o.x / (1.f + expf(-o.x)); o.y = o.y / (1.f + expf(-o.y));
      o.z = o.z / (1.f + expf(-o.z)); o.w = o.w / (1.f + expf(-o.w));
    }
    *(float4*)(C + (size_t)row * N + bn + tn * 4) = o;
  }
}

// ---------------- NN fp32 GEMM (small): out[m,n] = sum_k A[m,k]*B[k,n] ----------------
// BM=BN=64, BK=16, 256 threads, 4x4 per thread
__global__ __launch_bounds__(256) void gemm_nn64(const float* __restrict__ A, int lda,
                                                 const float* __restrict__ B, int ldb,
                                                 float* __restrict__ C, int ldc, int K)
{
  __shared__ float As[16][64];
  __shared__ float Bs[16][64];
  const int tid = threadIdx.x;
  const int bm = blockIdx.y * 64, bn = blockIdx.x * 64;
  const int tm = tid >> 4, tn = tid & 15;
  const int lr = tid >> 2, lc = (tid & 3) * 4;   // A loader
  const int br = tid >> 4, bc = (tid & 15) * 4;  // B loader
  float acc[4][4];
#pragma unroll
  for (int i = 0; i < 4; i++)
#pragma unroll
    for (int j = 0; j < 4; j++) acc[i][j] = 0.f;

  for (int k0 = 0; k0 < K; k0 += 16) {
    float4 a0 = *(const float4*)(A + (size_t)(bm + lr) * lda + k0 + lc);
    float4 b0 = *(const float4*)(B + (size_t)(k0 + br) * ldb + bn + bc);
    __syncthreads();
    As[lc + 0][lr] = a0.x; As[lc + 1][lr] = a0.y; As[lc + 2][lr] = a0.z; As[lc + 3][lr] = a0.w;
    *(float4*)&Bs[br][bc] = b0;
    __syncthreads();
#pragma unroll
    for (int kk = 0; kk < 16; kk++) {
      float4 av = *(const float4*)&As[kk][tm * 4];
      float4 bv = *(const float4*)&Bs[kk][tn * 4];
      float a[4] = {av.x, av.y, av.z, av.w};
      float b[4] = {bv.x, bv.y, bv.z, bv.w};
#pragma unroll
      for (int i = 0; i < 4; i++)
#pragma unroll
        for (int j = 0; j < 4; j++) acc[i][j] += a[i] * b[j];
    }
  }
#pragma unroll
  for (int i = 0; i < 4; i++) {
    int row = bm + tm * 4 + i;
    float4 o = {acc[i][0], acc[i][1], acc[i][2], acc[i][3]};
    *(float4*)(C + (size_t)row * ldc + bn + tn * 4) = o;
  }
}

// ---------------- bias fold: b12[n] = sum_h bq[h(+512)] * ke[n,h] ----------------
__global__ void build_bias(const float* __restrict__ bq, const float* __restrict__ ke1,
                           const float* __restrict__ ke2, float* __restrict__ b12)
{
  int n = blockIdx.x * 256 + threadIdx.x;
  const float* ke = (n < NKEY) ? (ke1 + (size_t)n * HALF) : (ke2 + (size_t)(n - NKEY) * HALF);
  const float* bb = (n < NKEY) ? bq : (bq + HALF);
  float s = 0.f;
  for (int h = 0; h < HALF; ++h) s += bb[h] * ke[h];
  b12[n] = s;
}

// ---------------- per-token top-k ----------------
__device__ __forceinline__ void wave_argmax(float& bv, int& bi)
{
#pragma unroll
  for (int off = 1; off < 64; off <<= 1) {
    float ov = __shfl_xor(bv, off, 64);
    int   oi = __shfl_xor(bi, off, 64);
    if (ov > bv || (ov == bv && oi < bi)) { bv = ov; bi = oi; }
  }
}

__device__ __forceinline__ void topk32of512(float v[8], int lane, float* outv, int* outi)
{
  for (int it = 0; it < TOPK; ++it) {
    float bv = v[0]; int bi = lane;
#pragma unroll
    for (int j = 1; j < 8; j++) {
      if (v[j] > bv) { bv = v[j]; bi = lane + (j << 6); }
    }
    wave_argmax(bv, bi);
    if ((bi & 63) == lane) {
      const int j = bi >> 6;
#pragma unroll
      for (int q = 0; q < 8; q++) if (q == j) v[q] = -INFINITY;
      outv[it] = bv; outi[it] = bi;
    }
  }
}

__global__ __launch_bounds__(64) void topk_kernel(const float* __restrict__ S,
                                                  float* __restrict__ w_out,
                                                  int* __restrict__ idx_out)
{
  const int t = blockIdx.x;
  const int lane = threadIdx.x;
  const float* srow = S + (size_t)t * DIM;
  float v1[8], v2[8];
#pragma unroll
  for (int j = 0; j < 8; j++) {
    v1[j] = srow[lane + 64 * j];
    v2[j] = srow[HALF + lane + 64 * j];
  }
  __shared__ float s1v[TOPK]; __shared__ int s1i[TOPK];
  __shared__ float s2v[TOPK]; __shared__ int s2i[TOPK];
  __shared__ float topv[TOPK]; __shared__ int topi[TOPK];

  topk32of512(v1, lane, s1v, s1i);
  topk32of512(v2, lane, s2v, s2i);
  __syncthreads();

  // frontier candidates: 2 per lane
  float cv[2]; int cab[2];
#pragma unroll
  for (int s = 0; s < 2; s++) {
    int c = lane + 64 * s;
    if (c < 119) {
      int a = CAND_A[c], b = CAND_B[c];
      cv[s] = s1v[a] + s2v[b];
      cab[s] = (a << 5) | b;
    } else { cv[s] = -INFINITY; cab[s] = 0; }
  }

  for (int it = 0; it < TOPK; ++it) {
    float bv = cv[0]; int bi = lane;
    if (cv[1] > bv) { bv = cv[1]; bi = lane + 64; }
    wave_argmax(bv, bi);
    if ((bi & 63) == lane) {
      int s = bi >> 6;
      int ab = cab[s];
      cv[s] = -INFINITY;
      topv[it] = bv;
      topi[it] = s1i[ab >> 5] * NKEY + s2i[ab & 31];
    }
  }
  __syncthreads();

  // softmax over the 32 selected (scale 1/sqrt(1024) = 1/32)
  float e = 0.f;
  if (lane < TOPK) e = expf((topv[lane] - topv[0]) * 0.03125f);
  float tot = e;
#pragma unroll
  for (int off = 1; off < 64; off <<= 1) tot += __shfl_xor(tot, off, 64);
  if (lane < TOPK) {
    w_out[(size_t)t * TOPK + lane] = e / tot;
    idx_out[(size_t)t * TOPK + lane] = topi[lane];
  }
}

// ---------------- gather values, weighted sum, apply gate ----------------
__global__ __launch_bounds__(256) void gather_gate(const float* __restrict__ values,
                                                   const float* __restrict__ wv,
                                                   const int* __restrict__ widx,
                                                   const float* __restrict__ gate,
                                                   float* __restrict__ pre)
{
  const int t = blockIdx.x;
  const int tid = threadIdx.x;
  __shared__ float w[TOPK]; __shared__ int ix[TOPK];
  if (tid < TOPK) { w[tid] = wv[(size_t)t * TOPK + tid]; ix[tid] = widx[(size_t)t * TOPK + tid]; }
  __syncthreads();
  const float4* V = (const float4*)values;
  float4 acc = make_float4(0.f, 0.f, 0.f, 0.f);
#pragma unroll 8
  for (int k = 0; k < TOPK; k++) {
    float4 r = V[(size_t)ix[k] * (DIM / 4) + tid];
    float wk = w[k];
    acc.x += wk * r.x; acc.y += wk * r.y; acc.z += wk * r.z; acc.w += wk * r.w;
  }
  float4 g = ((const float4*)gate)[(size_t)t * (DIM / 4) + tid];
  acc.x *= g.x; acc.y *= g.y; acc.z *= g.z; acc.w *= g.w;
  ((float4*)pre)[(size_t)t * (DIM / 4) + tid] = acc;
}

// ---------------- host ----------------
extern "C" void kernel_launch(void* const* d_in, const int* in_sizes, int n_in,
                              void* d_out, int out_size, void* d_ws, size_t ws_size,
                              hipStream_t stream)
{
  const float* x      = (const float*)d_in[0];
  const float* ke1    = (const float*)d_in[1];
  const float* ke2    = (const float*)d_in[2];
  const float* values = (const float*)d_in[3];
  const float* Wq     = (const float*)d_in[4];
  const float* bq     = (const float*)d_in[5];
  const float* Wg     = (const float*)d_in[6];
  const float* bg     = (const float*)d_in[7];
  const float* Wo     = (const float*)d_in[8];
  const float* bo     = (const float*)d_in[9];
  float* out = (float*)d_out;

  float* ws  = (float*)d_ws;
  float* Ct  = ws;                                    // 1024*1024
  float* b12 = Ct + (size_t)DIM * DIM;                // 1024
  float* S   = b12 + DIM;                             // 4096*1024 (reused as 'pre')
  float* G   = S + (size_t)NTOK * DIM;                // 4096*1024
  float* w32 = G + (size_t)NTOK * DIM;                // 4096*32
  int*   i32 = (int*)(w32 + (size_t)NTOK * TOPK);     // 4096*32

  // fold Wq into key embeddings: Ct[n,d]
  gemm_nn64<<<dim3(16, 8), 256, 0, stream>>>(ke1, HALF, Wq, DIM, Ct, DIM, HALF);
  gemm_nn64<<<dim3(16, 8), 256, 0, stream>>>(ke2, HALF, Wq + (size_t)HALF * DIM, DIM,
                                             Ct + (size_t)NKEY * DIM, DIM, HALF);
  build_bias<<<4, 256, 0, stream>>>(bq, ke1, ke2, b12);

  // scores[t,n] = x . Ct[n] + b12[n]
  gemm_nt<<<dim3(DIM / 64, NTOK / 128), 256, 0, stream>>>(x, Ct, b12, S, NTOK, DIM, DIM, 0);
  // gate = silu(x . Wg[e] + bg)
  gemm_nt<<<dim3(DIM / 64, NTOK / 128), 256, 0, stream>>>(x, Wg, bg, G, NTOK, DIM, DIM, 1);

  topk_kernel<<<NTOK, 64, 0, stream>>>(S, w32, i32);
  gather_gate<<<NTOK, 256, 0, stream>>>(values, w32, i32, G, S);

  // out = pre . Wo[e] + bo
  gemm_nt<<<dim3(DIM / 64, NTOK / 128), 256, 0, stream>>>(S, Wo, bo, out, NTOK, DIM, DIM, 0);
}